// Round 4
// baseline (199.857 us; speedup 1.0000x reference)
//
#include <hip/hip_runtime.h>
#include <math.h>

// R4: f16 tables in d_ws (L2-resident). 8 lanes/edge, EIGHT edges per
// macro-iteration: 32 independent 16B loads in flight, recursive-halving
// transpose reduction (21 shuffles/8 edges, result for edge e0+r lands on
// lane r), full-wave epilogue (transcendentals amortized over 64 edges/wave),
// coalesced stores. __launch_bounds__(256,4) caps VGPR at 128.

typedef _Float16 h2 __attribute__((ext_vector_type(2)));
union U16 { uint4 u; h2 h[4]; };
union HU { uint u; h2 h; };

// ---------- fused conversion kernel: both tables f32 -> f16 ------------------
__global__ __launch_bounds__(256) void cvt_f16_fused_kernel(
    const float4* __restrict__ srcA, int nA4,
    const float4* __restrict__ srcB, int nB4,
    uint2* __restrict__ dst)
{
    int i = blockIdx.x * blockDim.x + threadIdx.x;
    if (i >= nA4 + nB4) return;
    float4 f = (i < nA4) ? srcA[i] : srcB[i - nA4];
    HU a, b;
    a.h = h2{(_Float16)f.x, (_Float16)f.y};
    b.h = h2{(_Float16)f.z, (_Float16)f.w};
    dst[i] = make_uint2(a.u, b.u);
}

// 8-lane recursive-halving transpose-reduce: input x0..x7 are per-lane partials
// for edges e0..e0+7; returns (sum over the 8 lanes) of edge e0+r on lane r.
__device__ __forceinline__ float reduce8t(
    float x0, float x1, float x2, float x3,
    float x4, float x5, float x6, float x7, int r)
{
    const bool h1 = (r & 1), h2b = (r & 2), h4 = (r & 4);
    float b0 = (h1 ? x1 : x0) + __shfl_xor(h1 ? x0 : x1, 1, 8);
    float b1 = (h1 ? x3 : x2) + __shfl_xor(h1 ? x2 : x3, 1, 8);
    float b2 = (h1 ? x5 : x4) + __shfl_xor(h1 ? x4 : x5, 1, 8);
    float b3 = (h1 ? x7 : x6) + __shfl_xor(h1 ? x6 : x7, 1, 8);
    float c0 = (h2b ? b1 : b0) + __shfl_xor(h2b ? b0 : b1, 2, 8);
    float c1 = (h2b ? b3 : b2) + __shfl_xor(h2b ? b2 : b3, 2, 8);
    return (h4 ? c1 : c0) + __shfl_xor(h4 ? c0 : c1, 4, 8);
}

// ---------- main edge kernel -------------------------------------------------
__global__ __launch_bounds__(256, 4) void zinb_edge8_kernel(
    const _Float16* __restrict__ uhalf,   // [n_cells, 128]
    const _Float16* __restrict__ ihalf,   // [n_genes, 128]
    const float* __restrict__ ge_factor,
    const float* __restrict__ sz_factor,
    const float* __restrict__ W_mean, const float* __restrict__ b_mean,
    const float* __restrict__ W_disp, const float* __restrict__ b_disp,
    const float* __restrict__ W_pi,   const float* __restrict__ b_pi,
    const int* __restrict__ src_idx,
    const int* __restrict__ dst_idx,
    float* __restrict__ out,              // [3E]: mu | disp | pi
    int E)
{
    const int tid = threadIdx.x;
    const int r = tid & 7;
    const int slot = (blockIdx.x * blockDim.x + tid) >> 3;
    const int n_slots = (gridDim.x * blockDim.x) >> 3;

    // W slices as f16 pairs: lane r owns elems [r*8, r*8+8) and [64+r*8, ...)
    h2 wm[8], wd[8], wp[8];
#pragma unroll
    for (int c = 0; c < 2; ++c)
#pragma unroll
        for (int j = 0; j < 4; ++j) {
            int k = c * 64 + r * 8 + 2 * j;
            wm[c * 4 + j] = h2{(_Float16)W_mean[k], (_Float16)W_mean[k + 1]};
            wd[c * 4 + j] = h2{(_Float16)W_disp[k], (_Float16)W_disp[k + 1]};
            wp[c * 4 + j] = h2{(_Float16)W_pi[k],   (_Float16)W_pi[k + 1]};
        }
    const float bm = b_mean[0], bd = b_disp[0], bp = b_pi[0];

    const int nmac = E >> 3;  // macro-groups of 8 edges
    const int4* src4 = (const int4*)src_idx;
    const int4* dst4 = (const int4*)dst_idx;

    for (int q = slot; q < nmac; q += n_slots) {
        const int e0 = q << 3;

        // group-uniform indices for all 8 edges
        const int4 s03 = src4[2 * q];
        const int4 s47 = src4[2 * q + 1];
        const int4 g03 = dst4[2 * q];
        const int4 g47 = dst4[2 * q + 1];
        const int s[8] = {s03.x, s03.y, s03.z, s03.w, s47.x, s47.y, s47.z, s47.w};
        const int g[8] = {g03.x, g03.y, g03.z, g03.w, g47.x, g47.y, g47.z, g47.w};

        // per-lane own-edge idx + factor gathers, issued early
        const int  se  = src_idx[e0 + r];
        const int  de  = dst_idx[e0 + r];
        const float szf = sz_factor[se];
        const float gef = ge_factor[de];

        float am[8], ad[8], ap[8];
#pragma unroll
        for (int j = 0; j < 8; ++j) {
            const uint4* up = (const uint4*)(uhalf + (size_t)s[j] * 128);
            const uint4* vp = (const uint4*)(ihalf + (size_t)g[j] * 128);
            U16 u0, u1, v0, v1;
            u0.u = up[r]; u1.u = up[r + 8];
            v0.u = vp[r]; v1.u = vp[r + 8];

            float m = 0.f, dd = 0.f, pp = 0.f;
#pragma unroll
            for (int jj = 0; jj < 4; ++jj) {
                h2 p0 = u0.h[jj] * v0.h[jj];
                m  = __builtin_amdgcn_fdot2(p0, wm[jj], m,  false);
                dd = __builtin_amdgcn_fdot2(p0, wd[jj], dd, false);
                pp = __builtin_amdgcn_fdot2(p0, wp[jj], pp, false);
                h2 p1 = u1.h[jj] * v1.h[jj];
                m  = __builtin_amdgcn_fdot2(p1, wm[4 + jj], m,  false);
                dd = __builtin_amdgcn_fdot2(p1, wd[4 + jj], dd, false);
                pp = __builtin_amdgcn_fdot2(p1, wp[4 + jj], pp, false);
            }
            am[j] = m; ad[j] = dd; ap[j] = pp;
        }

        // transpose-reduce: lane r ends with edge e0+r's three sums
        const float rm = reduce8t(am[0], am[1], am[2], am[3], am[4], am[5], am[6], am[7], r);
        const float rd = reduce8t(ad[0], ad[1], ad[2], ad[3], ad[4], ad[5], ad[6], ad[7], r);
        const float rp = reduce8t(ap[0], ap[1], ap[2], ap[3], ap[4], ap[5], ap[6], ap[7], r);

        // full-wave epilogue (each lane = one edge)
        const float mu_ = 1.f / (1.f + __expf(-(rm + bm)));
        const float pi  = 1.f / (1.f + __expf(-(rp + bp)));
        const float xd  = gef * (rd + bd);
        const float sp  = fmaxf(xd, 0.f) + __logf(1.f + __expf(-fabsf(xd)));
        const float disp = fminf(fmaxf(sp, 1e-4f), 1e4f);
        const float mu = szf * fminf(fmaxf(__expf(gef * mu_) - 1.f, 1e-5f), 1e6f);

        const int e = e0 + r;
        out[e]                 = mu;
        out[(size_t)E + e]     = disp;
        out[(size_t)2 * E + e] = pi;
    }
}

// ---------- tail kernel: last E%8 edges, scalar f32 --------------------------
__global__ void zinb_tail_kernel(
    const float* __restrict__ ufeats, const float* __restrict__ ifeats,
    const float* __restrict__ ge_factor, const float* __restrict__ sz_factor,
    const float* __restrict__ W_mean, const float* __restrict__ b_mean,
    const float* __restrict__ W_disp, const float* __restrict__ b_disp,
    const float* __restrict__ W_pi,   const float* __restrict__ b_pi,
    const int* __restrict__ src_idx, const int* __restrict__ dst_idx,
    float* __restrict__ out, int E, int start)
{
    int e = start + blockIdx.x * blockDim.x + threadIdx.x;
    if (e >= E) return;
    const int s = src_idx[e], g = dst_idx[e];
    float am = 0.f, ad = 0.f, ap = 0.f;
    for (int k = 0; k < 128; ++k) {
        float h = ufeats[(size_t)s * 128 + k] * ifeats[(size_t)g * 128 + k];
        am = fmaf(h, W_mean[k], am);
        ad = fmaf(h, W_disp[k], ad);
        ap = fmaf(h, W_pi[k],   ap);
    }
    const float gef = ge_factor[g];
    const float szf = sz_factor[s];
    const float mu_ = 1.f / (1.f + __expf(-(am + b_mean[0])));
    const float pi  = 1.f / (1.f + __expf(-(ap + b_pi[0])));
    const float xd  = gef * (ad + b_disp[0]);
    const float sp  = fmaxf(xd, 0.f) + __logf(1.f + __expf(-fabsf(xd)));
    const float disp = fminf(fmaxf(sp, 1e-4f), 1e4f);
    const float mu = szf * fminf(fmaxf(__expf(gef * mu_) - 1.f, 1e-5f), 1e6f);
    out[e] = mu; out[(size_t)E + e] = disp; out[(size_t)2 * E + e] = pi;
}

// ---------- fallback: pure-f32 kernel (ws too small) -------------------------
__global__ __launch_bounds__(256) void zinb_edge_f32_kernel(
    const float* __restrict__ ufeats, const float* __restrict__ ifeats,
    const float* __restrict__ ge_factor, const float* __restrict__ sz_factor,
    const float* __restrict__ W_mean, const float* __restrict__ b_mean,
    const float* __restrict__ W_disp, const float* __restrict__ b_disp,
    const float* __restrict__ W_pi,   const float* __restrict__ b_pi,
    const int* __restrict__ src_idx, const int* __restrict__ dst_idx,
    float* __restrict__ out, int E)
{
    const int r = threadIdx.x & 7;
    const int slot = (blockIdx.x * blockDim.x + threadIdx.x) >> 3;
    const int n_slots = (gridDim.x * blockDim.x) >> 3;

    float4 wm[4], wd[4], wp[4];
    {
        const float4* wm4 = (const float4*)W_mean + r;
        const float4* wd4 = (const float4*)W_disp + r;
        const float4* wp4 = (const float4*)W_pi   + r;
#pragma unroll
        for (int c = 0; c < 4; ++c) { wm[c] = wm4[c*8]; wd[c] = wd4[c*8]; wp[c] = wp4[c*8]; }
    }
    const float bm = b_mean[0], bd = b_disp[0], bp = b_pi[0];

    for (int e = slot; e < E; e += n_slots) {
        const int s = src_idx[e];
        const int g = dst_idx[e];
        const float4* u4 = (const float4*)(ufeats + (size_t)s * 128) + r;
        const float4* v4 = (const float4*)(ifeats + (size_t)g * 128) + r;
        float am = 0.f, ad = 0.f, ap = 0.f;
#pragma unroll
        for (int c = 0; c < 4; ++c) {
            float4 u = u4[c*8]; float4 v = v4[c*8];
            float px = u.x*v.x, py = u.y*v.y, pz = u.z*v.z, pw = u.w*v.w;
            am = fmaf(px, wm[c].x, am); am = fmaf(py, wm[c].y, am);
            am = fmaf(pz, wm[c].z, am); am = fmaf(pw, wm[c].w, am);
            ad = fmaf(px, wd[c].x, ad); ad = fmaf(py, wd[c].y, ad);
            ad = fmaf(pz, wd[c].z, ad); ad = fmaf(pw, wd[c].w, ad);
            ap = fmaf(px, wp[c].x, ap); ap = fmaf(py, wp[c].y, ap);
            ap = fmaf(pw, wp[c].w, ap); ap = fmaf(pz, wp[c].z, ap);
        }
#pragma unroll
        for (int off = 1; off < 8; off <<= 1) {
            am += __shfl_xor(am, off); ad += __shfl_xor(ad, off); ap += __shfl_xor(ap, off);
        }
        if (r == 0) {
            const float gef = ge_factor[g];
            const float szf = sz_factor[s];
            const float mu_ = 1.f / (1.f + __expf(-(am + bm)));
            const float pi  = 1.f / (1.f + __expf(-(ap + bp)));
            const float xd  = gef * (ad + bd);
            const float sp  = fmaxf(xd, 0.f) + __logf(1.f + __expf(-fabsf(xd)));
            const float disp = fminf(fmaxf(sp, 1e-4f), 1e4f);
            const float mu = szf * fminf(fmaxf(__expf(gef * mu_) - 1.f, 1e-5f), 1e6f);
            out[e] = mu; out[(size_t)E + e] = disp; out[(size_t)2*E + e] = pi;
        }
    }
}

extern "C" void kernel_launch(void* const* d_in, const int* in_sizes, int n_in,
                              void* d_out, int out_size, void* d_ws, size_t ws_size,
                              hipStream_t stream) {
    const float* ufeats    = (const float*)d_in[0];
    const float* ifeats    = (const float*)d_in[1];
    const float* ge_factor = (const float*)d_in[2];
    const float* sz_factor = (const float*)d_in[3];
    const float* W_mean    = (const float*)d_in[4];
    const float* b_mean    = (const float*)d_in[5];
    const float* W_disp    = (const float*)d_in[6];
    const float* b_disp    = (const float*)d_in[7];
    const float* W_pi      = (const float*)d_in[8];
    const float* b_pi      = (const float*)d_in[9];
    const int*   src_idx   = (const int*)d_in[10];
    const int*   dst_idx   = (const int*)d_in[11];
    float* out = (float*)d_out;

    const int E       = in_sizes[10];
    const int n_cells = in_sizes[0] / 128;
    const int n_genes = in_sizes[1] / 128;

    const size_t u_elems = (size_t)n_cells * 128;
    const size_t i_elems = (size_t)n_genes * 128;
    const size_t ws_needed = (u_elems + i_elems) * sizeof(_Float16);

    if (ws_size >= ws_needed) {
        _Float16* uhalf = (_Float16*)d_ws;
        _Float16* ihalf = uhalf + u_elems;

        const int un4 = (int)(u_elems / 4);
        const int in4 = (int)(i_elems / 4);
        const int n4  = un4 + in4;
        hipLaunchKernelGGL(cvt_f16_fused_kernel, dim3((n4 + 255) / 256), dim3(256), 0, stream,
                           (const float4*)ufeats, un4, (const float4*)ifeats, in4,
                           (uint2*)d_ws);

        hipLaunchKernelGGL(zinb_edge8_kernel, dim3(4096), dim3(256), 0, stream,
                           uhalf, ihalf, ge_factor, sz_factor,
                           W_mean, b_mean, W_disp, b_disp, W_pi, b_pi,
                           src_idx, dst_idx, out, E);

        const int rem = E & 7;
        if (rem) {
            hipLaunchKernelGGL(zinb_tail_kernel, dim3(1), dim3(64), 0, stream,
                               ufeats, ifeats, ge_factor, sz_factor,
                               W_mean, b_mean, W_disp, b_disp, W_pi, b_pi,
                               src_idx, dst_idx, out, E, E - rem);
        }
    } else {
        hipLaunchKernelGGL(zinb_edge_f32_kernel, dim3(2048), dim3(256), 0, stream,
                           ufeats, ifeats, ge_factor, sz_factor,
                           W_mean, b_mean, W_disp, b_disp, W_pi, b_pi,
                           src_idx, dst_idx, out, E);
    }
}

// Round 5
// 143.913 us; speedup vs baseline: 1.3887x; 1.3887x over previous
//
#include <hip/hip_runtime.h>
#include <math.h>

// R5: f16 tables in d_ws (L2-resident). 8 lanes/edge, 8 edges/macro-iteration.
// All 32 feature loads issued up front as explicit named scalars (no arrays ->
// no scratch), __launch_bounds__(256,2) so VGPR cap is 256 (R4's (256,4)=128
// cap forced scratch spill: VGPR=64 + FETCH 236MB/WRITE 154MB of spill traffic).
// Transpose-reduce (7 shfl per acc-set), full-wave epilogue, coalesced stores.

typedef _Float16 h2 __attribute__((ext_vector_type(2)));
union U16 { uint4 u; h2 h[4]; };
union HU { uint u; h2 h; };

// ---------- fused conversion kernel: both tables f32 -> f16 ------------------
__global__ __launch_bounds__(256) void cvt_f16_fused_kernel(
    const float4* __restrict__ srcA, int nA4,
    const float4* __restrict__ srcB, int nB4,
    uint2* __restrict__ dst)
{
    int i = blockIdx.x * blockDim.x + threadIdx.x;
    if (i >= nA4 + nB4) return;
    float4 f = (i < nA4) ? srcA[i] : srcB[i - nA4];
    HU a, b;
    a.h = h2{(_Float16)f.x, (_Float16)f.y};
    b.h = h2{(_Float16)f.z, (_Float16)f.w};
    dst[i] = make_uint2(a.u, b.u);
}

// 8-lane recursive-halving transpose-reduce: x0..x7 are per-lane partials for
// edges e0..e0+7; returns the full 8-lane sum of edge e0+r on lane r.
__device__ __forceinline__ float reduce8t(
    float x0, float x1, float x2, float x3,
    float x4, float x5, float x6, float x7, int r)
{
    const bool h1 = (r & 1), h2b = (r & 2), h4 = (r & 4);
    float b0 = (h1 ? x1 : x0) + __shfl_xor(h1 ? x0 : x1, 1, 8);
    float b1 = (h1 ? x3 : x2) + __shfl_xor(h1 ? x2 : x3, 1, 8);
    float b2 = (h1 ? x5 : x4) + __shfl_xor(h1 ? x4 : x5, 1, 8);
    float b3 = (h1 ? x7 : x6) + __shfl_xor(h1 ? x6 : x7, 1, 8);
    float c0 = (h2b ? b1 : b0) + __shfl_xor(h2b ? b0 : b1, 2, 8);
    float c1 = (h2b ? b3 : b2) + __shfl_xor(h2b ? b2 : b3, 2, 8);
    return (h4 ? c1 : c0) + __shfl_xor(h4 ? c0 : c1, 4, 8);
}

// 24 fdot2 for one edge's 64 elements held by this lane.
__device__ __forceinline__ void dot3(
    const U16& ua, const U16& ub, const U16& va, const U16& vb,
    const h2* wm, const h2* wd, const h2* wp,
    float& m, float& dd, float& pp)
{
#pragma unroll
    for (int jj = 0; jj < 4; ++jj) {
        h2 p0 = ua.h[jj] * va.h[jj];
        m  = __builtin_amdgcn_fdot2(p0, wm[jj], m,  false);
        dd = __builtin_amdgcn_fdot2(p0, wd[jj], dd, false);
        pp = __builtin_amdgcn_fdot2(p0, wp[jj], pp, false);
        h2 p1 = ub.h[jj] * vb.h[jj];
        m  = __builtin_amdgcn_fdot2(p1, wm[4 + jj], m,  false);
        dd = __builtin_amdgcn_fdot2(p1, wd[4 + jj], dd, false);
        pp = __builtin_amdgcn_fdot2(p1, wp[4 + jj], pp, false);
    }
}

#define LOADE(J, SJ, GJ)                                                  \
    const uint4* uP##J = (const uint4*)(uhalf + (size_t)(SJ) * 128);      \
    const uint4* vP##J = (const uint4*)(ihalf + (size_t)(GJ) * 128);      \
    U16 uA##J, uB##J, vA##J, vB##J;                                       \
    uA##J.u = uP##J[r]; uB##J.u = uP##J[r + 8];                           \
    vA##J.u = vP##J[r]; vB##J.u = vP##J[r + 8];

// ---------- main edge kernel -------------------------------------------------
__global__ __launch_bounds__(256, 2) void zinb_edge8_kernel(
    const _Float16* __restrict__ uhalf,   // [n_cells, 128]
    const _Float16* __restrict__ ihalf,   // [n_genes, 128]
    const float* __restrict__ ge_factor,
    const float* __restrict__ sz_factor,
    const float* __restrict__ W_mean, const float* __restrict__ b_mean,
    const float* __restrict__ W_disp, const float* __restrict__ b_disp,
    const float* __restrict__ W_pi,   const float* __restrict__ b_pi,
    const int* __restrict__ src_idx,
    const int* __restrict__ dst_idx,
    float* __restrict__ out,              // [3E]: mu | disp | pi
    int E)
{
    const int tid = threadIdx.x;
    const int r = tid & 7;
    const int slot = (blockIdx.x * blockDim.x + tid) >> 3;
    const int n_slots = (gridDim.x * blockDim.x) >> 3;

    // W slices as f16 pairs: lane r owns elems [r*8, r*8+8) and [64+r*8, ...)
    h2 wm[8], wd[8], wp[8];
#pragma unroll
    for (int c = 0; c < 2; ++c)
#pragma unroll
        for (int j = 0; j < 4; ++j) {
            int k = c * 64 + r * 8 + 2 * j;
            wm[c * 4 + j] = h2{(_Float16)W_mean[k], (_Float16)W_mean[k + 1]};
            wd[c * 4 + j] = h2{(_Float16)W_disp[k], (_Float16)W_disp[k + 1]};
            wp[c * 4 + j] = h2{(_Float16)W_pi[k],   (_Float16)W_pi[k + 1]};
        }
    const float bm = b_mean[0], bd = b_disp[0], bp = b_pi[0];

    const int nmac = E >> 3;
    const int4* src4 = (const int4*)src_idx;
    const int4* dst4 = (const int4*)dst_idx;

    for (int q = slot; q < nmac; q += n_slots) {
        const int e0 = q << 3;

        const int4 s03 = src4[2 * q];
        const int4 s47 = src4[2 * q + 1];
        const int4 g03 = dst4[2 * q];
        const int4 g47 = dst4[2 * q + 1];

        // per-lane own-edge factor gathers (hit the same L1/L2 lines as above)
        const int  se  = src_idx[e0 + r];
        const int  de  = dst_idx[e0 + r];
        const float szf = sz_factor[se];
        const float gef = ge_factor[de];

        // all 32 feature loads issued before any consumption
        LOADE(0, s03.x, g03.x)
        LOADE(1, s03.y, g03.y)
        LOADE(2, s03.z, g03.z)
        LOADE(3, s03.w, g03.w)
        LOADE(4, s47.x, g47.x)
        LOADE(5, s47.y, g47.y)
        LOADE(6, s47.z, g47.z)
        LOADE(7, s47.w, g47.w)

        float m0 = 0.f, d0 = 0.f, p0 = 0.f; dot3(uA0, uB0, vA0, vB0, wm, wd, wp, m0, d0, p0);
        float m1 = 0.f, d1 = 0.f, p1 = 0.f; dot3(uA1, uB1, vA1, vB1, wm, wd, wp, m1, d1, p1);
        float m2 = 0.f, d2 = 0.f, p2 = 0.f; dot3(uA2, uB2, vA2, vB2, wm, wd, wp, m2, d2, p2);
        float m3 = 0.f, d3 = 0.f, p3 = 0.f; dot3(uA3, uB3, vA3, vB3, wm, wd, wp, m3, d3, p3);
        float m4 = 0.f, d4 = 0.f, p4 = 0.f; dot3(uA4, uB4, vA4, vB4, wm, wd, wp, m4, d4, p4);
        float m5 = 0.f, d5 = 0.f, p5 = 0.f; dot3(uA5, uB5, vA5, vB5, wm, wd, wp, m5, d5, p5);
        float m6 = 0.f, d6 = 0.f, p6 = 0.f; dot3(uA6, uB6, vA6, vB6, wm, wd, wp, m6, d6, p6);
        float m7 = 0.f, d7 = 0.f, p7 = 0.f; dot3(uA7, uB7, vA7, vB7, wm, wd, wp, m7, d7, p7);

        const float rm = reduce8t(m0, m1, m2, m3, m4, m5, m6, m7, r);
        const float rd = reduce8t(d0, d1, d2, d3, d4, d5, d6, d7, r);
        const float rp = reduce8t(p0, p1, p2, p3, p4, p5, p6, p7, r);

        // full-wave epilogue (each lane = one edge)
        const float mu_ = 1.f / (1.f + __expf(-(rm + bm)));
        const float pi  = 1.f / (1.f + __expf(-(rp + bp)));
        const float xd  = gef * (rd + bd);
        const float sp  = fmaxf(xd, 0.f) + __logf(1.f + __expf(-fabsf(xd)));
        const float disp = fminf(fmaxf(sp, 1e-4f), 1e4f);
        const float mu = szf * fminf(fmaxf(__expf(gef * mu_) - 1.f, 1e-5f), 1e6f);

        const int e = e0 + r;
        out[e]                 = mu;
        out[(size_t)E + e]     = disp;
        out[(size_t)2 * E + e] = pi;
    }
}

// ---------- tail kernel: last E%8 edges, scalar f32 --------------------------
__global__ void zinb_tail_kernel(
    const float* __restrict__ ufeats, const float* __restrict__ ifeats,
    const float* __restrict__ ge_factor, const float* __restrict__ sz_factor,
    const float* __restrict__ W_mean, const float* __restrict__ b_mean,
    const float* __restrict__ W_disp, const float* __restrict__ b_disp,
    const float* __restrict__ W_pi,   const float* __restrict__ b_pi,
    const int* __restrict__ src_idx, const int* __restrict__ dst_idx,
    float* __restrict__ out, int E, int start)
{
    int e = start + blockIdx.x * blockDim.x + threadIdx.x;
    if (e >= E) return;
    const int s = src_idx[e], g = dst_idx[e];
    float am = 0.f, ad = 0.f, ap = 0.f;
    for (int k = 0; k < 128; ++k) {
        float h = ufeats[(size_t)s * 128 + k] * ifeats[(size_t)g * 128 + k];
        am = fmaf(h, W_mean[k], am);
        ad = fmaf(h, W_disp[k], ad);
        ap = fmaf(h, W_pi[k],   ap);
    }
    const float gef = ge_factor[g];
    const float szf = sz_factor[s];
    const float mu_ = 1.f / (1.f + __expf(-(am + b_mean[0])));
    const float pi  = 1.f / (1.f + __expf(-(ap + b_pi[0])));
    const float xd  = gef * (ad + b_disp[0]);
    const float sp  = fmaxf(xd, 0.f) + __logf(1.f + __expf(-fabsf(xd)));
    const float disp = fminf(fmaxf(sp, 1e-4f), 1e4f);
    const float mu = szf * fminf(fmaxf(__expf(gef * mu_) - 1.f, 1e-5f), 1e6f);
    out[e] = mu; out[(size_t)E + e] = disp; out[(size_t)2 * E + e] = pi;
}

// ---------- fallback: pure-f32 kernel (ws too small) -------------------------
__global__ __launch_bounds__(256) void zinb_edge_f32_kernel(
    const float* __restrict__ ufeats, const float* __restrict__ ifeats,
    const float* __restrict__ ge_factor, const float* __restrict__ sz_factor,
    const float* __restrict__ W_mean, const float* __restrict__ b_mean,
    const float* __restrict__ W_disp, const float* __restrict__ b_disp,
    const float* __restrict__ W_pi,   const float* __restrict__ b_pi,
    const int* __restrict__ src_idx, const int* __restrict__ dst_idx,
    float* __restrict__ out, int E)
{
    const int r = threadIdx.x & 7;
    const int slot = (blockIdx.x * blockDim.x + threadIdx.x) >> 3;
    const int n_slots = (gridDim.x * blockDim.x) >> 3;

    float4 wm[4], wd[4], wp[4];
    {
        const float4* wm4 = (const float4*)W_mean + r;
        const float4* wd4 = (const float4*)W_disp + r;
        const float4* wp4 = (const float4*)W_pi   + r;
#pragma unroll
        for (int c = 0; c < 4; ++c) { wm[c] = wm4[c*8]; wd[c] = wd4[c*8]; wp[c] = wp4[c*8]; }
    }
    const float bm = b_mean[0], bd = b_disp[0], bp = b_pi[0];

    for (int e = slot; e < E; e += n_slots) {
        const int s = src_idx[e];
        const int g = dst_idx[e];
        const float4* u4 = (const float4*)(ufeats + (size_t)s * 128) + r;
        const float4* v4 = (const float4*)(ifeats + (size_t)g * 128) + r;
        float am = 0.f, ad = 0.f, ap = 0.f;
#pragma unroll
        for (int c = 0; c < 4; ++c) {
            float4 u = u4[c*8]; float4 v = v4[c*8];
            float px = u.x*v.x, py = u.y*v.y, pz = u.z*v.z, pw = u.w*v.w;
            am = fmaf(px, wm[c].x, am); am = fmaf(py, wm[c].y, am);
            am = fmaf(pz, wm[c].z, am); am = fmaf(pw, wm[c].w, am);
            ad = fmaf(px, wd[c].x, ad); ad = fmaf(py, wd[c].y, ad);
            ad = fmaf(pz, wd[c].z, ad); ad = fmaf(pw, wd[c].w, ad);
            ap = fmaf(px, wp[c].x, ap); ap = fmaf(py, wp[c].y, ap);
            ap = fmaf(pz, wp[c].z, ap); ap = fmaf(pw, wp[c].w, ap);
        }
#pragma unroll
        for (int off = 1; off < 8; off <<= 1) {
            am += __shfl_xor(am, off); ad += __shfl_xor(ad, off); ap += __shfl_xor(ap, off);
        }
        if (r == 0) {
            const float gef = ge_factor[g];
            const float szf = sz_factor[s];
            const float mu_ = 1.f / (1.f + __expf(-(am + bm)));
            const float pi  = 1.f / (1.f + __expf(-(ap + bp)));
            const float xd  = gef * (ad + bd);
            const float sp  = fmaxf(xd, 0.f) + __logf(1.f + __expf(-fabsf(xd)));
            const float disp = fminf(fmaxf(sp, 1e-4f), 1e4f);
            const float mu = szf * fminf(fmaxf(__expf(gef * mu_) - 1.f, 1e-5f), 1e6f);
            out[e] = mu; out[(size_t)E + e] = disp; out[(size_t)2*E + e] = pi;
        }
    }
}

extern "C" void kernel_launch(void* const* d_in, const int* in_sizes, int n_in,
                              void* d_out, int out_size, void* d_ws, size_t ws_size,
                              hipStream_t stream) {
    const float* ufeats    = (const float*)d_in[0];
    const float* ifeats    = (const float*)d_in[1];
    const float* ge_factor = (const float*)d_in[2];
    const float* sz_factor = (const float*)d_in[3];
    const float* W_mean    = (const float*)d_in[4];
    const float* b_mean    = (const float*)d_in[5];
    const float* W_disp    = (const float*)d_in[6];
    const float* b_disp    = (const float*)d_in[7];
    const float* W_pi      = (const float*)d_in[8];
    const float* b_pi      = (const float*)d_in[9];
    const int*   src_idx   = (const int*)d_in[10];
    const int*   dst_idx   = (const int*)d_in[11];
    float* out = (float*)d_out;

    const int E       = in_sizes[10];
    const int n_cells = in_sizes[0] / 128;
    const int n_genes = in_sizes[1] / 128;

    const size_t u_elems = (size_t)n_cells * 128;
    const size_t i_elems = (size_t)n_genes * 128;
    const size_t ws_needed = (u_elems + i_elems) * sizeof(_Float16);

    if (ws_size >= ws_needed) {
        _Float16* uhalf = (_Float16*)d_ws;
        _Float16* ihalf = uhalf + u_elems;

        const int un4 = (int)(u_elems / 4);
        const int in4 = (int)(i_elems / 4);
        const int n4  = un4 + in4;
        hipLaunchKernelGGL(cvt_f16_fused_kernel, dim3((n4 + 255) / 256), dim3(256), 0, stream,
                           (const float4*)ufeats, un4, (const float4*)ifeats, in4,
                           (uint2*)d_ws);

        hipLaunchKernelGGL(zinb_edge8_kernel, dim3(2048), dim3(256), 0, stream,
                           uhalf, ihalf, ge_factor, sz_factor,
                           W_mean, b_mean, W_disp, b_disp, W_pi, b_pi,
                           src_idx, dst_idx, out, E);

        const int rem = E & 7;
        if (rem) {
            hipLaunchKernelGGL(zinb_tail_kernel, dim3(1), dim3(64), 0, stream,
                               ufeats, ifeats, ge_factor, sz_factor,
                               W_mean, b_mean, W_disp, b_disp, W_pi, b_pi,
                               src_idx, dst_idx, out, E, E - rem);
        }
    } else {
        hipLaunchKernelGGL(zinb_edge_f32_kernel, dim3(2048), dim3(256), 0, stream,
                           ufeats, ifeats, ge_factor, sz_factor,
                           W_mean, b_mean, W_disp, b_disp, W_pi, b_pi,
                           src_idx, dst_idx, out, E);
    }
}